// Round 3
// baseline (568.012 us; speedup 1.0000x reference)
//
#include <hip/hip_runtime.h>

// BSplineBasis: T=262144 samples, K=512 cubic B-spline bases, clamped knots
// (516 fp32). Only 4 bases/row are nonzero; output dense (T,512) fp32 = 512 MiB.
//
// R1/R2 post-mortem: single-kernel variants (selects, or zero+window with
// per-block barriers) both plateau at ~3 TB/s effective write BW -- per-block
// LDS staging + final barrier chained to one wave's serial binary search
// poisons every 32-KiB block's critical path. The device's own fillBuffer
// (no LDS, no barriers, grid-stride) demonstrates 6.2 TB/s pure-write.
//
// R3: split into (A) a fillBuffer-shaped zero kernel and (B) a tiny window
// kernel writing full aligned 128-B lines (no partial-line RMW).

namespace {
constexpr int K_N  = 512;
constexpr int NKN  = 516;
constexpr int DEG  = 3;
constexpr float EPSF = 1e-6f;
constexpr int BLK  = 256;
constexpr int ROWS_PER_BLK_B = 32;   // kernel B: 8 threads per row
}

// ---- Kernel A: pure streaming zero-fill (mimics __amd_rocclr_fillBufferAligned) ----
__global__ __launch_bounds__(BLK)
void zero_fill_kernel(float4* __restrict__ out4, int n4)
{
    const int stride = gridDim.x * BLK;
    const float4 z = make_float4(0.f, 0.f, 0.f, 0.f);
    for (int i = blockIdx.x * BLK + threadIdx.x; i < n4; i += stride)
        out4[i] = z;
}

// ---- Kernel B: write the 1-2 full 128-B lines containing each row's window ----
__global__ __launch_bounds__(BLK)
void window_kernel(const float* __restrict__ t_arr,
                   const float* __restrict__ knots,
                   float* __restrict__ out)
{
    __shared__ float kv[NKN];
    const int tid = threadIdx.x;
    for (int i = tid; i < NKN; i += BLK) kv[i] = knots[i];
    __syncthreads();

    const int q   = tid & 7;                         // float4 slot within a line
    const int row = blockIdx.x * ROWS_PER_BLK_B + (tid >> 3);
    const float t = t_arr[row];

    // Reference semantics: t >= kv[512] (t >= 1.0) => all-zero row (the closed
    // last degree-0 interval dies at d=1 since kv[515]-kv[514]=0 < EPS).
    if (t >= kv[K_N]) return;                        // zeros already written by kernel A

    // Largest s in [3,511] with kv[s] <= t, identical fp32 comparisons to the
    // reference's degree-0 test (kv[s] <= t < kv[s+1]).
    int lo = DEG, hi = K_N - 1;
    while (lo < hi) {
        const int mid = (lo + hi + 1) >> 1;
        if (t >= kv[mid]) lo = mid; else hi = mid - 1;
    }
    const int s = lo;

    // Local Cox-de Boor with the reference's den>=EPS guards.
    float N[4] = {1.f, 0.f, 0.f, 0.f};
    #pragma unroll
    for (int d = 1; d <= DEG; ++d) {
        float nn[4];
        #pragma unroll
        for (int k = 0; k <= d; ++k) {
            const int j = s - d + k;
            const float left  = (k >= 1)     ? N[k - 1] : 0.f;
            const float right = (k <= d - 1) ? N[k]     : 0.f;
            const float den1 = kv[j + d]     - kv[j];
            const float den2 = kv[j + d + 1] - kv[j + 1];
            const float c1 = (den1 >= EPSF) ? (t - kv[j]) / den1 : 0.f;
            const float c2 = (den2 >= EPSF) ? (kv[j + d + 1] - t) / den2 : 0.f;
            nn[k] = c1 * left + c2 * right;
        }
        #pragma unroll
        for (int k = 0; k <= d; ++k) N[k] = nn[k];
    }
    const int j0 = s - DEG;                          // first nonzero col, [0,508]

    float4* row4 = reinterpret_cast<float4*>(out + (size_t)row * K_N);
    const int l0 = j0 >> 5;                          // 32 floats per 128-B line
    const int l1 = (j0 + 3) >> 5;                    // <= 15

    // Line l0: lanes q=0..7 write consecutive float4s (one coalesced line).
    {
        const int cbase = (l0 << 5) + (q << 2);
        float e[4];
        #pragma unroll
        for (int k = 0; k < 4; ++k) {
            const int rel = cbase + k - j0;
            e[k] = (rel == 0) ? N[0] : (rel == 1) ? N[1]
                 : (rel == 2) ? N[2] : (rel == 3) ? N[3] : 0.f;
        }
        row4[(l0 << 3) + q] = make_float4(e[0], e[1], e[2], e[3]);
    }
    if (l1 != l0) {                                  // window crosses a line boundary
        const int cbase = (l1 << 5) + (q << 2);
        float e[4];
        #pragma unroll
        for (int k = 0; k < 4; ++k) {
            const int rel = cbase + k - j0;
            e[k] = (rel == 0) ? N[0] : (rel == 1) ? N[1]
                 : (rel == 2) ? N[2] : (rel == 3) ? N[3] : 0.f;
        }
        row4[(l1 << 3) + q] = make_float4(e[0], e[1], e[2], e[3]);
    }
}

extern "C" void kernel_launch(void* const* d_in, const int* in_sizes, int n_in,
                              void* d_out, int out_size, void* d_ws, size_t ws_size,
                              hipStream_t stream) {
    const float* t_arr = (const float*)d_in[0];
    const float* knots = (const float*)d_in[1];
    float* out = (float*)d_out;
    const int n_rows = in_sizes[0];                  // 262144
    const int n4 = (n_rows * K_N) / 4;               // 33,554,432 float4s

    // A: 2048 blocks x 256 threads -> 64 float4 stores/thread, grid-stride.
    hipLaunchKernelGGL(zero_fill_kernel, dim3(2048), dim3(BLK), 0, stream,
                       reinterpret_cast<float4*>(out), n4);
    // B: 8 threads/row, 32 rows/block.
    hipLaunchKernelGGL(window_kernel, dim3(n_rows / ROWS_PER_BLK_B), dim3(BLK), 0, stream,
                       t_arr, knots, out);
}

// Round 4
// 529.675 us; speedup vs baseline: 1.0724x; 1.0724x over previous
//
#include <hip/hip_runtime.h>

// BSplineBasis: T=262144 rows, K=512 cubic bases, clamped knots (516 fp32).
// Only 4 bases/row nonzero; dense (T,512) fp32 output = 512 MiB -> write-BW-bound,
// floor = 537 MB / 6.2 TB/s ~= 86 us (+ ~435 us fixed harness poison fills in the
// timed region per R1-R3 evidence).
//
// R4: leanest single-kernel form. 256 rows/block; every thread computes its own
// row's window (parallel binary search, no serial-wave dependency), one barrier,
// then a pure streaming store loop whose common case is "store zero" (2 cmps +
// branch + dwordx4 store); the <=2 float4s/row overlapping the window take a
// rare divergent path with broadcast LDS reads.

namespace {
constexpr int K_N  = 512;    // output columns
constexpr int F4PR = K_N/4;  // 128 float4 per row
constexpr int NKN  = 516;    // knots
constexpr int DEG  = 3;
constexpr float EPSF = 1e-6f;
constexpr int BLK  = 256;    // threads per block
constexpr int ROWS = 256;    // rows per block (1 per thread)
}

__global__ __launch_bounds__(BLK)
void bspline_basis_kernel(const float* __restrict__ t_arr,
                          const float* __restrict__ knots,
                          float* __restrict__ out)
{
    __shared__ float kv[NKN];
    __shared__ float vals[ROWS][5];   // pad 4->5: phase-1 write stride breaks 8-way conflicts
    __shared__ int   j0s[ROWS];

    const int tid = threadIdx.x;
    for (int i = tid; i < NKN; i += BLK) kv[i] = knots[i];
    __syncthreads();

    const int row_base = blockIdx.x * ROWS;

    // ---- Phase 1: each thread computes its own row's window ----
    {
        const float t = t_arr[row_base + tid];
        int   j0 = -1000;            // sentinel: all-zero row
        float N[4] = {1.f, 0.f, 0.f, 0.f};
        // Reference: t >= kv[512] (t >= 1.0) => all-zero row (closed last
        // degree-0 interval dies at d=1, kv[515]-kv[514]=0 < EPS).
        if (t < kv[K_N]) {
            // Largest s in [3,511] with kv[s] <= t (same fp32 compares as ref).
            int lo = DEG, hi = K_N - 1;
            while (lo < hi) {
                const int mid = (lo + hi + 1) >> 1;
                if (t >= kv[mid]) lo = mid; else hi = mid - 1;
            }
            const int s = lo;
            #pragma unroll
            for (int d = 1; d <= DEG; ++d) {
                float nn[4];
                #pragma unroll
                for (int k = 0; k <= d; ++k) {
                    const int j = s - d + k;
                    const float left  = (k >= 1)     ? N[k - 1] : 0.f;
                    const float right = (k <= d - 1) ? N[k]     : 0.f;
                    const float den1 = kv[j + d]     - kv[j];
                    const float den2 = kv[j + d + 1] - kv[j + 1];
                    const float c1 = (den1 >= EPSF) ? (t - kv[j]) / den1 : 0.f;
                    const float c2 = (den2 >= EPSF) ? (kv[j + d + 1] - t) / den2 : 0.f;
                    nn[k] = c1 * left + c2 * right;
                }
                #pragma unroll
                for (int k = 0; k <= d; ++k) N[k] = nn[k];
            }
            j0 = s - DEG;            // [0, 508]
        }
        j0s[tid] = j0;
        vals[tid][0] = N[0]; vals[tid][1] = N[1];
        vals[tid][2] = N[2]; vals[tid][3] = N[3];
    }
    __syncthreads();

    // ---- Phase 2: stream 256x512 floats; common case = store zero ----
    float4* out4 = reinterpret_cast<float4*>(out + (size_t)row_base * K_N);
    const float4 z = make_float4(0.f, 0.f, 0.f, 0.f);
    constexpr int TOTAL_F4 = ROWS * F4PR;            // 32768 float4 / block
    #pragma unroll 4
    for (int it = 0; it < TOTAL_F4 / BLK; ++it) {    // 128 stores / thread
        const int idx = it * BLK + tid;              // consecutive lanes -> consecutive 16B
        const int r   = idx >> 7;                    // row (uniform per wave)
        const int c   = (idx & 127) << 2;            // first column of this float4
        const int j0  = j0s[r];                      // wave-uniform LDS broadcast
        float4 v = z;
        if (c <= j0 + 3 && c + 3 >= j0) {            // rare: <=2 lanes per affected wave
            float e[4];
            #pragma unroll
            for (int k = 0; k < 4; ++k) {
                const int rel = c + k - j0;
                e[k] = (rel >= 0 && rel <= 3) ? vals[r][rel] : 0.f;
            }
            v = make_float4(e[0], e[1], e[2], e[3]);
        }
        out4[idx] = v;
    }
}

extern "C" void kernel_launch(void* const* d_in, const int* in_sizes, int n_in,
                              void* d_out, int out_size, void* d_ws, size_t ws_size,
                              hipStream_t stream) {
    const float* t_arr = (const float*)d_in[0];
    const float* knots = (const float*)d_in[1];
    float* out = (float*)d_out;
    const int n_rows = in_sizes[0];                  // 262144, divisible by ROWS
    dim3 grid(n_rows / ROWS);                        // 1024 blocks
    hipLaunchKernelGGL(bspline_basis_kernel, grid, dim3(BLK), 0, stream,
                       t_arr, knots, out);
}